// Round 5
// baseline (224.338 us; speedup 1.0000x reference)
//
#include <hip/hip_runtime.h>

// Causal single-head attention, B=4 S=4096 Dm=256 Dqk=64, fp32 in/out.
// R13: barrier-free attention main loop. Evidence: R8/R9/R11 (three different
// barrier-synced structures) all 51-71us with every pipe <37% busy; the cost
// is the per-iter barrier convoy + P's LDS round-trip (145KB/block-iter).
// Fix: P never touches LDS. S^T's D-layout has lane=q, and A/B MFMA fragment
// layouts are identical (proven by proj's af/bf indexing), so P becomes the
// PV B-operand directly: mfma(V_frag, P_frag) -> O^T[m=e][n=q]. The k-halves
// the other lane-half holds are fetched with __shfl_xor(.,32) (proven in
// repack_store) + cndmask select. Each wave owns (ks-slice 32k x 2 qsubs x
// 4 e-tiles), oa[2][4] private; ZERO barriers over jt. Once-per-block LDS
// epilogue (2 phases) reduces the 4 ks-partials and transposes for coalesced
// stores. Blocks = 4 waves/256thr, grid 960 (e-half split; S^T duplicated x2
// across eh — MFMA was at 18%, free). V read once per block-iter (no dup).
// den keeps the exact old sum order -> dfin bitwise identical; O reassociates
// only (<< 0.0156 tol). proj/combine/ws layout unchanged from R12.
// ws: qf 2MB + kf 2MB + vf 8MB + Op 7.34MB + Dp 98KB = 19.5MB.

#define BATCH 4
#define SEQ   4096
#define DM    256
#define DQK   64

typedef __bf16 bf16x8 __attribute__((ext_vector_type(8)));
typedef __bf16 bf16x2 __attribute__((ext_vector_type(2)));
typedef float  f32x16 __attribute__((ext_vector_type(16)));

// HW RNE float->bf16 (v_cvt_pk_bf16_f32 via compiler).
__device__ __forceinline__ unsigned short f2bf(float f) {
    __bf16 h = (__bf16)f;
    return __builtin_bit_cast(unsigned short, h);
}
__device__ __forceinline__ unsigned int pk2bf(float lo, float hi) {
    bf16x2 v = {(__bf16)lo, (__bf16)hi};    // elem0 low, elem1 high
    return __builtin_bit_cast(unsigned int, v);
}
__device__ __forceinline__ bf16x8 u4bf(uint4 u) { return __builtin_bit_cast(bf16x8, u); }

// Repack a 32x32x16 MFMA accumulator D[m][n] (C-layout: col(n)=lane&31,
// row(m)=(r&3)+8(r>>2)+4(lane>>5)) into two 1KB fragment chunks where the
// fragment k-dim = m and lane-dim = n, then store. (Verified R2/R3.)
__device__ __forceinline__ void repack_store(const f32x16& acc, int q2, int l,
                                             uint4* __restrict__ out, size_t tile_ofs_u4) {
    unsigned int d0[4], d1[4], p0[4], p1[4];
#pragma unroll
    for (int h = 0; h < 4; ++h) {
        d0[h] = pk2bf(acc[4*h + 0], acc[4*h + 1]);
        d1[h] = pk2bf(acc[4*h + 2], acc[4*h + 3]);
        p0[h] = __shfl_xor((int)d0[h], 32);
        p1[h] = __shfl_xor((int)d1[h], 32);
    }
#pragma unroll
    for (int kc = 0; kc < 2; ++kc) {
        int h = 2*kc + q2;
        uint4 v = (q2 == 0) ? make_uint4(d0[h], d1[h], p0[h], p1[h])
                            : make_uint4(p0[h], p1[h], d0[h], d1[h]);
        out[tile_ofs_u4 + (size_t)kc * 64 + l] = v;
    }
}

// R3 task map: nc=1 (T<12), 2 (12..23), 3 (24..31).
__device__ __forceinline__ int obase(int T) {
    return (T < 24) ? (T - 12) : 12 + (T - 24) * 2;
}
__device__ __forceinline__ int dbase(int T) {
    return (T < 24) ? (T - 12) * 2 : 24 + (T - 24) * 3;
}

// ---------------------------------------------------------------------------
// Fused projection. grid (64 s-tiles, 4 batch, 3): z=0 Q, z=1 K, z=2 V (all
// 4 e-chunks; Xv staged once).  (Unchanged from R12.)
// ---------------------------------------------------------------------------
__global__ __launch_bounds__(256) void proj(const float* __restrict__ Xq,
                                            const float* __restrict__ Xk,
                                            const float* __restrict__ Xv,
                                            const float* __restrict__ Wq,
                                            const float* __restrict__ Wk,
                                            const float* __restrict__ Wv,
                                            uint4* __restrict__ qf,
                                            uint4* __restrict__ kf,
                                            uint4* __restrict__ vf) {
    __shared__ unsigned short Xs[64][264];
    __shared__ unsigned short Ws[64][264];

    const int z = blockIdx.z;
    const int bx = blockIdx.x, b = blockIdx.y;
    const float* X = (z == 0) ? Xq : (z == 1) ? Xk : Xv;
    const float* W = (z == 0) ? Wq : (z == 1) ? Wk : Wv;
    const int s0 = bx * 64;
    const int tid = threadIdx.x, w = tid >> 6, l = tid & 63, ln = l & 31, q2 = l >> 5;

#pragma unroll
    for (int i = 0; i < 16; ++i) {
        int f = i * 256 + tid;
        int r = f >> 6, c4 = f & 63;
        float4 xv = *(const float4*)&X[((size_t)b * SEQ + s0 + r) * DM + c4 * 4];
        ushort4 h; h.x = f2bf(xv.x); h.y = f2bf(xv.y); h.z = f2bf(xv.z); h.w = f2bf(xv.w);
        *(ushort4*)&Xs[r][c4 * 4] = h;
    }

    if (z < 2) {
#pragma unroll
        for (int i = 0; i < 16; ++i) {
            int f = i * 256 + tid;
            int r = f >> 6, c4 = f & 63;
            float4 wv = *(const float4*)&W[(size_t)r * DM + c4 * 4];
            ushort4 h; h.x = f2bf(wv.x); h.y = f2bf(wv.y); h.z = f2bf(wv.z); h.w = f2bf(wv.w);
            *(ushort4*)&Ws[r][c4 * 4] = h;
        }
        __syncthreads();
        const int msub = w >> 1, nsub = w & 1;
        f32x16 a0 = {}, a1 = {};
#pragma unroll
        for (int c = 0; c < 16; c += 2) {
            bf16x8 af0 = u4bf(*(const uint4*)&Ws[msub*32 + ln][c*16 + q2*8]);
            bf16x8 bf0 = u4bf(*(const uint4*)&Xs[nsub*32 + ln][c*16 + q2*8]);
            a0 = __builtin_amdgcn_mfma_f32_32x32x16_bf16(af0, bf0, a0, 0, 0, 0);
            bf16x8 af1 = u4bf(*(const uint4*)&Ws[msub*32 + ln][(c+1)*16 + q2*8]);
            bf16x8 bf1 = u4bf(*(const uint4*)&Xs[nsub*32 + ln][(c+1)*16 + q2*8]);
            a1 = __builtin_amdgcn_mfma_f32_32x32x16_bf16(af1, bf1, a1, 0, 0, 0);
        }
        f32x16 acc = a0 + a1;
        size_t base = (((size_t)(b*128 + bx*2 + nsub)) * 4 + 2*msub) * 64;
        repack_store(acc, q2, l, (z == 0) ? qf : kf, base);
    } else {
        const int msub = w & 1, nsub = w >> 1;
        for (int ec = 0; ec < 4; ++ec) {
            __syncthreads();
#pragma unroll
            for (int i = 0; i < 16; ++i) {
                int f = i * 256 + tid;
                int r = f >> 6, c4 = f & 63;
                float4 wv = *(const float4*)&W[(size_t)(ec*64 + r) * DM + c4 * 4];
                ushort4 h; h.x = f2bf(wv.x); h.y = f2bf(wv.y); h.z = f2bf(wv.z); h.w = f2bf(wv.w);
                *(ushort4*)&Ws[r][c4 * 4] = h;
            }
            __syncthreads();
            f32x16 a0 = {}, a1 = {};
#pragma unroll
            for (int c = 0; c < 16; c += 2) {
                bf16x8 af0 = u4bf(*(const uint4*)&Xs[msub*32 + ln][c*16 + q2*8]);
                bf16x8 bf0 = u4bf(*(const uint4*)&Ws[nsub*32 + ln][c*16 + q2*8]);
                a0 = __builtin_amdgcn_mfma_f32_32x32x16_bf16(af0, bf0, a0, 0, 0, 0);
                bf16x8 af1 = u4bf(*(const uint4*)&Xs[msub*32 + ln][(c+1)*16 + q2*8]);
                bf16x8 bf1 = u4bf(*(const uint4*)&Ws[nsub*32 + ln][(c+1)*16 + q2*8]);
                a1 = __builtin_amdgcn_mfma_f32_32x32x16_bf16(af1, bf1, a1, 0, 0, 0);
            }
            f32x16 acc = a0 + a1;
            int et = ec*2 + nsub;
            size_t base = (((size_t)(b*8 + et)) * 256 + (size_t)bx*4 + msub*2) * 64;
            repack_store(acc, q2, l, vf, base);
        }
    }
}

// ---------------------------------------------------------------------------
// Attention. 960 blocks x 256 thr. bid = ((task*2+eh)<<3)|slot; slot: b,qh
// (XCD pin). Block covers 64 q-rows (qh) x 128 e-cols (eh) x K-chunk [j0,j1).
// Wave w=ks (0..3): per iter, S^T for both qsubs (8 MFMA, dup across eh),
// exp/mask -> P held IN REGISTERS as PV B-operand (shfl_xor(32) + select
// builds the cross-half k-words), PV: oa[2 qs][4 et] += V x P (16 MFMA).
// NO barriers in the main loop; waves fully independent. Epilogue: den
// reduction (bitwise-identical order to R12) + 2-phase LDS ks-reduction /
// transpose -> coalesced float4 stores.
// ---------------------------------------------------------------------------
__global__ __launch_bounds__(256, 2) void attn(const uint4* __restrict__ qf,
                                               const uint4* __restrict__ kf,
                                               const uint4* __restrict__ vf,
                                               float* __restrict__ out,
                                               unsigned short* __restrict__ Op,
                                               float* __restrict__ Dp) {
    __shared__ float Lep[4][2][2][32][36];   // [ks][qs][eti][q][e+pad] 73.7KB
    __shared__ float denp[4][2][64];         // [ks][qs][lane]
    __shared__ float dfin[64];

    const int bid = blockIdx.x;
    const int slot = bid & 7;
    const int b = slot >> 1, qh = slot & 1;
    const int te = bid >> 3;                 // [0,120)
    const int task = te >> 1, eh = te & 1;
    int T, cc, nc;
    if (task < 12)      { T = task;                cc = 0;               nc = 1; }
    else if (task < 36) { int q = task - 12; T = 12 + (q >> 1); cc = q & 1;       nc = 2; }
    else                { int q = task - 36; T = 24 + q / 3;    cc = q - 3*(q/3); nc = 3; }
    const int n = T + 1;
    const int j0 = cc * n / nc, j1 = (cc + 1) * n / nc;

    const int tid = threadIdx.x, w = tid >> 6, l = tid & 63, ln = l & 31, q2 = l >> 5;
    const int ks = w;
    const float cfac = 0.18033688011112042f; // log2(e)/sqrt(64)

    bf16x8 qv[2][4];
#pragma unroll
    for (int qs = 0; qs < 2; ++qs)
#pragma unroll
        for (int c = 0; c < 4; ++c)
            qv[qs][c] = u4bf(qf[(((size_t)b*128 + T*4 + qh*2 + qs) * 4 + c) * 64 + l]);

    uint4 kaf[4];
#pragma unroll
    for (int c = 0; c < 4; ++c)
        kaf[c] = kf[(((size_t)b*128 + j0*4 + ks) * 4 + c) * 64 + l];

    f32x16 oa[2][4] = {};
    float den[2] = {0.f, 0.f};

    for (int jt = j0; jt < j1; ++jt) {
        const bool diag = (jt == T);

        // ---- V frags for this iter: A-operand layout == vf layout as-is ----
        uint4 vbs[4][2];
#pragma unroll
        for (int e4 = 0; e4 < 4; ++e4)
#pragma unroll
            for (int t = 0; t < 2; ++t)
                vbs[e4][t] = vf[(((size_t)b*8 + eh*4 + e4) * 256 + (size_t)jt*8 + ks*2 + t) * 64 + l];

        // ---- S^T for both qsubs (interleaved chains) ----
        f32x16 s0 = {}, s1 = {};
#pragma unroll
        for (int c = 0; c < 4; ++c) {
            bf16x8 ka = u4bf(kaf[c]);
            s0 = __builtin_amdgcn_mfma_f32_32x32x16_bf16(ka, qv[0][c], s0, 0, 0, 0);
            s1 = __builtin_amdgcn_mfma_f32_32x32x16_bf16(ka, qv[1][c], s1, 0, 0, 0);
        }
        // prefetch next K frags (in place; latency covered by exp+PV)
        if (jt + 1 < j1) {
#pragma unroll
            for (int c = 0; c < 4; ++c)
                kaf[c] = kf[(((size_t)b*128 + (jt+1)*4 + ks) * 4 + c) * 64 + l];
        }

        // ---- exp/mask -> in-register P as PV B-operand ----
        // pv[r] = P[k=(r&3)+8(r>>2)+4q2][q=ln]; B-frag word j of 16-k step t
        // needs k = 8*q2 + 2j (+16t): own half + shfl_xor(32) partner half.
        uint4 pB[2][2];
#pragma unroll
        for (int qs = 0; qs < 2; ++qs) {
            const f32x16 s = qs ? s1 : s0;
            const int qsub = qh*2 + qs;
            float pd = 0.f;
            unsigned int own[8];
#pragma unroll
            for (int hq = 0; hq < 4; ++hq) {
                float ev[4];
#pragma unroll
                for (int i = 0; i < 4; ++i) {
                    float e = __builtin_exp2f(s[4*hq + i] * cfac);
                    if (diag) {
                        int klocal = 4*q2 + i + 8*hq;
                        if (ks*32 + klocal > qsub*32 + ln) e = 0.f;
                    }
                    pd += e; ev[i] = e;
                }
                own[2*hq]     = pk2bf(ev[0], ev[1]);
                own[2*hq + 1] = pk2bf(ev[2], ev[3]);
            }
            den[qs] += pd;
            unsigned int xo[8];
#pragma unroll
            for (int i = 0; i < 8; ++i)
                xo[i] = (unsigned int)__shfl_xor((int)own[i], 32);
            // t=0: k 0..15 ; t=1: k 16..31 (verified word-by-word vs layout)
            pB[qs][0] = make_uint4(q2 ? xo[2] : own[0], q2 ? xo[3] : own[1],
                                   q2 ? own[2] : xo[0], q2 ? own[3] : xo[1]);
            pB[qs][1] = make_uint4(q2 ? xo[6] : own[4], q2 ? xo[7] : own[5],
                                   q2 ? own[6] : xo[4], q2 ? own[7] : xo[5]);
        }

        // ---- PV: oa[qs][e4] += V^T x P  (D[m=e][n=q]) ----
#pragma unroll
        for (int e4 = 0; e4 < 4; ++e4) {
            bf16x8 va0 = u4bf(vbs[e4][0]);
            bf16x8 va1 = u4bf(vbs[e4][1]);
#pragma unroll
            for (int qs = 0; qs < 2; ++qs) {
                oa[qs][e4] = __builtin_amdgcn_mfma_f32_32x32x16_bf16(va0, u4bf(pB[qs][0]), oa[qs][e4], 0, 0, 0);
                oa[qs][e4] = __builtin_amdgcn_mfma_f32_32x32x16_bf16(va1, u4bf(pB[qs][1]), oa[qs][e4], 0, 0, 0);
            }
        }
    }

    // ---- den reduction (same order as R12 -> bitwise-identical dfin) ----
    denp[ks][0][l] = den[0];
    denp[ks][1][l] = den[1];
    __syncthreads();
    if (tid < 64) {
        int qsl = tid >> 5, qln = tid & 31;
        float sden = 0.f;
#pragma unroll
        for (int p = 0; p < 4; ++p)
#pragma unroll
            for (int hh = 0; hh < 2; ++hh)
                sden += denp[p][qsl][hh*32 + qln];
        dfin[tid] = (nc == 1) ? 1.0f / sden : sden;
    }
    __syncthreads();
    if (eh == 0 && nc > 1 && tid < 64)
        Dp[((size_t)b*48 + dbase(T) + cc) * 128 + qh*64 + tid] = dfin[tid];

    // ---- O epilogue: reduce 4 ks-partials, transpose, store (2 phases) ----
    const int qr  = (tid >> 3) & 31;
    const int e4r = tid & 7;
#pragma unroll
    for (int ph = 0; ph < 2; ++ph) {
        // writers: oa[qs][ph*2+eti] rows 4h..4h+3 are e = 8h+4q2 .. +3 at q=ln
#pragma unroll
        for (int qs = 0; qs < 2; ++qs)
#pragma unroll
            for (int eti = 0; eti < 2; ++eti) {
                const f32x16 a = oa[qs][ph*2 + eti];
#pragma unroll
                for (int h = 0; h < 4; ++h) {
                    float4 v4 = make_float4(a[4*h], a[4*h+1], a[4*h+2], a[4*h+3]);
                    *(float4*)&Lep[ks][qs][eti][ln][8*h + 4*q2] = v4;
                }
            }
        __syncthreads();
#pragma unroll
        for (int qs = 0; qs < 2; ++qs)
#pragma unroll
            for (int eti = 0; eti < 2; ++eti) {
                float4 sum = make_float4(0.f, 0.f, 0.f, 0.f);
#pragma unroll
                for (int p = 0; p < 4; ++p) {
                    float4 v = *(const float4*)&Lep[p][qs][eti][qr][4*e4r];
                    sum.x += v.x; sum.y += v.y; sum.z += v.z; sum.w += v.w;
                }
                const int qrow = qh*64 + qs*32 + qr;
                const int eg   = eh*128 + (ph*2 + eti)*32 + 4*e4r;
                if (nc == 1) {
                    float d = dfin[qs*32 + qr];
                    float4 o = make_float4(sum.x*d, sum.y*d, sum.z*d, sum.w*d);
                    *(float4*)&out[((size_t)b*SEQ + T*128 + qrow) * DM + eg] = o;
                } else if (cc == 0) {
                    *(float4*)&out[((size_t)b*SEQ + T*128 + qrow) * DM + eg] = sum;
                } else {
                    size_t pidx = (size_t)b*28 + obase(T) + (cc - 1);
                    uint2 u;
                    u.x = pk2bf(sum.x, sum.y);
                    u.y = pk2bf(sum.z, sum.w);
                    *(uint2*)&Op[(pidx*128 + qrow) * DM + eg] = u;
                }
            }
        if (ph == 0) __syncthreads();
    }
}

// ---------------------------------------------------------------------------
// Combine partials for T in [12,32). grid (20, 4, 4 q-quarters) x 256 thr.
// (Unchanged.)
// ---------------------------------------------------------------------------
__global__ __launch_bounds__(256) void combine(const unsigned short* __restrict__ Op,
                                               const float* __restrict__ Dp,
                                               float* __restrict__ out) {
    const int T = 12 + blockIdx.x, b = blockIdx.y, qq = blockIdx.z;
    const int nc = (T < 24) ? 2 : 3;
    const int t = threadIdx.x;
    const size_t db = (size_t)b*48 + dbase(T);
    const size_t pb = (size_t)b*28 + obase(T);
#pragma unroll 4
    for (int r = 0; r < 32; ++r) {
        int q = qq*32 + r;
        size_t oofs = ((size_t)b*SEQ + T*128 + q) * DM + t;
        float sum = out[oofs];
        float dsum = 0.f;
        for (int c = 0; c < nc; ++c) dsum += Dp[(db + c)*128 + q];
        for (int c = 1; c < nc; ++c) {
            unsigned int uv = Op[((pb + c - 1)*128 + q) * DM + t];
            sum += __builtin_bit_cast(float, uv << 16);
        }
        out[oofs] = sum / dsum;
    }
}

// ---------------------------------------------------------------------------
extern "C" void kernel_launch(void* const* d_in, const int* in_sizes, int n_in,
                              void* d_out, int out_size, void* d_ws, size_t ws_size,
                              hipStream_t stream) {
    const float* enc_q = (const float*)d_in[0];
    const float* enc_k = (const float*)d_in[1];
    const float* enc_v = (const float*)d_in[2];
    // d_in[3] = mask (deterministic causal triu) — not needed
    const float* Wq = (const float*)d_in[4];
    const float* Wk = (const float*)d_in[5];
    const float* Wv = (const float*)d_in[6];
    float* out = (float*)d_out;

    uint4* qf = (uint4*)d_ws;                              // 2MB
    uint4* kf = qf + 131072;                               // 2MB
    uint4* vf = kf + 131072;                               // 8MB
    unsigned short* Op = (unsigned short*)(vf + 524288);   // [4][28][128][256] bf16, 7.34MB
    float* Dp = (float*)(Op + (size_t)4*28*128*256);       // [4][48][128] f32, 98KB

    proj<<<dim3(64, 4, 3), 256, 0, stream>>>(enc_q, enc_k, enc_v, Wq, Wk, Wv, qf, kf, vf);
    attn<<<960, 256, 0, stream>>>(qf, kf, vf, out, Op, Dp);
    combine<<<dim3(20, 4, 4), 256, 0, stream>>>(Op, Dp, out);
}

// Round 6
// 212.249 us; speedup vs baseline: 1.0570x; 1.0570x over previous
//
#include <hip/hip_runtime.h>

// Causal single-head attention, B=4 S=4096 Dm=256 Dqk=64, fp32 in/out.
// R14: load-balance attn. R12 evidence: OccupancyPercent 15.8 with 2 blocks/CU
// resident (50% static) => utilization decays = imbalance tail. grid was 480 =
// exactly residency (no backfill), chunk lengths 1..12 k-tiles; makespan = max
// CU pair-sum ~ 24 iters (43us) vs 8.8 avg (15us). Effective busy time only
// ~14.5us of the 46us. Fix: enumerate the 528 (T,j) tile-cells of the causal
// triangle per (b,qh) in snake order; each of 60 blocks gets exactly 8-9
// consecutive cells (balanced +-1 by construction, every cell = identical
// work: 8 S^T MFMA + 16 PV MFMA). Per-T partials flushed with fire-and-forget
// atomicAdd (no vmcnt stall, order-free); out pre-zeroed via hipMemsetAsync;
// tiny normalize kernel divides by atomic den. Deletes task map/Op/Dp/combine;
// ws 19.5 -> 12.2MB. Iteration body, Pb double-buffer, slot XCD-pinning
// bit-identical to R12 (attn core proven 46us, VGPR 72, 2 blocks/CU).
// Numerics: only summation order changes (~1e-6 rel); bf16 P/V quantization
// dominates absmax (0.015625) as before.
// ws: qf 2MB + kf 2MB + vf 8MB + Den 64KB = 12.2MB.

#define BATCH 4
#define SEQ   4096
#define DM    256
#define DQK   64
#define NCELL 528   // 32*33/2 tile-cells per (b,qh)

typedef __bf16 bf16x8 __attribute__((ext_vector_type(8)));
typedef __bf16 bf16x2 __attribute__((ext_vector_type(2)));
typedef float  f32x16 __attribute__((ext_vector_type(16)));

// HW RNE float->bf16 (v_cvt_pk_bf16_f32 via compiler).
__device__ __forceinline__ unsigned short f2bf(float f) {
    __bf16 h = (__bf16)f;
    return __builtin_bit_cast(unsigned short, h);
}
__device__ __forceinline__ unsigned int pk2bf(float lo, float hi) {
    bf16x2 v = {(__bf16)lo, (__bf16)hi};    // elem0 low, elem1 high
    return __builtin_bit_cast(unsigned int, v);
}
__device__ __forceinline__ bf16x8 u4bf(uint4 u) { return __builtin_bit_cast(bf16x8, u); }

// Repack a 32x32x16 MFMA accumulator D[m][n] (C-layout: col(n)=lane&31,
// row(m)=(r&3)+8(r>>2)+4(lane>>5)) into two 1KB fragment chunks where the
// fragment k-dim = m and lane-dim = n, then store. (Verified R2/R3.)
__device__ __forceinline__ void repack_store(const f32x16& acc, int q2, int l,
                                             uint4* __restrict__ out, size_t tile_ofs_u4) {
    unsigned int d0[4], d1[4], p0[4], p1[4];
#pragma unroll
    for (int h = 0; h < 4; ++h) {
        d0[h] = pk2bf(acc[4*h + 0], acc[4*h + 1]);
        d1[h] = pk2bf(acc[4*h + 2], acc[4*h + 3]);
        p0[h] = __shfl_xor((int)d0[h], 32);
        p1[h] = __shfl_xor((int)d1[h], 32);
    }
#pragma unroll
    for (int kc = 0; kc < 2; ++kc) {
        int h = 2*kc + q2;
        uint4 v = (q2 == 0) ? make_uint4(d0[h], d1[h], p0[h], p1[h])
                            : make_uint4(p0[h], p1[h], d0[h], d1[h]);
        out[tile_ofs_u4 + (size_t)kc * 64 + l] = v;
    }
}

// ---------------------------------------------------------------------------
// Fused projection. grid (64 s-tiles, 4 batch, 3): z=0 Q, z=1 K, z=2 V (all
// 4 e-chunks; Xv staged once).  (Unchanged from R12.)
// ---------------------------------------------------------------------------
__global__ __launch_bounds__(256) void proj(const float* __restrict__ Xq,
                                            const float* __restrict__ Xk,
                                            const float* __restrict__ Xv,
                                            const float* __restrict__ Wq,
                                            const float* __restrict__ Wk,
                                            const float* __restrict__ Wv,
                                            uint4* __restrict__ qf,
                                            uint4* __restrict__ kf,
                                            uint4* __restrict__ vf) {
    __shared__ unsigned short Xs[64][264];
    __shared__ unsigned short Ws[64][264];

    const int z = blockIdx.z;
    const int bx = blockIdx.x, b = blockIdx.y;
    const float* X = (z == 0) ? Xq : (z == 1) ? Xk : Xv;
    const float* W = (z == 0) ? Wq : (z == 1) ? Wk : Wv;
    const int s0 = bx * 64;
    const int tid = threadIdx.x, w = tid >> 6, l = tid & 63, ln = l & 31, q2 = l >> 5;

#pragma unroll
    for (int i = 0; i < 16; ++i) {
        int f = i * 256 + tid;
        int r = f >> 6, c4 = f & 63;
        float4 xv = *(const float4*)&X[((size_t)b * SEQ + s0 + r) * DM + c4 * 4];
        ushort4 h; h.x = f2bf(xv.x); h.y = f2bf(xv.y); h.z = f2bf(xv.z); h.w = f2bf(xv.w);
        *(ushort4*)&Xs[r][c4 * 4] = h;
    }

    if (z < 2) {
#pragma unroll
        for (int i = 0; i < 16; ++i) {
            int f = i * 256 + tid;
            int r = f >> 6, c4 = f & 63;
            float4 wv = *(const float4*)&W[(size_t)r * DM + c4 * 4];
            ushort4 h; h.x = f2bf(wv.x); h.y = f2bf(wv.y); h.z = f2bf(wv.z); h.w = f2bf(wv.w);
            *(ushort4*)&Ws[r][c4 * 4] = h;
        }
        __syncthreads();
        const int msub = w >> 1, nsub = w & 1;
        f32x16 a0 = {}, a1 = {};
#pragma unroll
        for (int c = 0; c < 16; c += 2) {
            bf16x8 af0 = u4bf(*(const uint4*)&Ws[msub*32 + ln][c*16 + q2*8]);
            bf16x8 bf0 = u4bf(*(const uint4*)&Xs[nsub*32 + ln][c*16 + q2*8]);
            a0 = __builtin_amdgcn_mfma_f32_32x32x16_bf16(af0, bf0, a0, 0, 0, 0);
            bf16x8 af1 = u4bf(*(const uint4*)&Ws[msub*32 + ln][(c+1)*16 + q2*8]);
            bf16x8 bf1 = u4bf(*(const uint4*)&Xs[nsub*32 + ln][(c+1)*16 + q2*8]);
            a1 = __builtin_amdgcn_mfma_f32_32x32x16_bf16(af1, bf1, a1, 0, 0, 0);
        }
        f32x16 acc = a0 + a1;
        size_t base = (((size_t)(b*128 + bx*2 + nsub)) * 4 + 2*msub) * 64;
        repack_store(acc, q2, l, (z == 0) ? qf : kf, base);
    } else {
        const int msub = w & 1, nsub = w >> 1;
        for (int ec = 0; ec < 4; ++ec) {
            __syncthreads();
#pragma unroll
            for (int i = 0; i < 16; ++i) {
                int f = i * 256 + tid;
                int r = f >> 6, c4 = f & 63;
                float4 wv = *(const float4*)&W[(size_t)(ec*64 + r) * DM + c4 * 4];
                ushort4 h; h.x = f2bf(wv.x); h.y = f2bf(wv.y); h.z = f2bf(wv.z); h.w = f2bf(wv.w);
                *(ushort4*)&Ws[r][c4 * 4] = h;
            }
            __syncthreads();
            f32x16 a0 = {}, a1 = {};
#pragma unroll
            for (int c = 0; c < 16; c += 2) {
                bf16x8 af0 = u4bf(*(const uint4*)&Xs[msub*32 + ln][c*16 + q2*8]);
                bf16x8 bf0 = u4bf(*(const uint4*)&Ws[nsub*32 + ln][c*16 + q2*8]);
                a0 = __builtin_amdgcn_mfma_f32_32x32x16_bf16(af0, bf0, a0, 0, 0, 0);
                bf16x8 af1 = u4bf(*(const uint4*)&Xs[msub*32 + ln][(c+1)*16 + q2*8]);
                bf16x8 bf1 = u4bf(*(const uint4*)&Ws[nsub*32 + ln][(c+1)*16 + q2*8]);
                a1 = __builtin_amdgcn_mfma_f32_32x32x16_bf16(af1, bf1, a1, 0, 0, 0);
            }
            f32x16 acc = a0 + a1;
            int et = ec*2 + nsub;
            size_t base = (((size_t)(b*8 + et)) * 256 + (size_t)bx*4 + msub*2) * 64;
            repack_store(acc, q2, l, vf, base);
        }
    }
}

// ---------------------------------------------------------------------------
// Attention. 480 blocks x 512 thr, 2 blocks/CU. slot = bid&7 -> b = slot>>1,
// qh = slot&1 (XCD pin, static). blk = bid>>3 in [0,60) covers snake cells
// c in [blk*528/60, (blk+1)*528/60) -> 8-9 cells, perfectly balanced.
// Cell c -> (T, j): T = tri-row, j = c - T(T+1)/2. Iteration body identical
// to R12: wave w: S^T (ks=w&3, qg=w>>2, qsub=qh*2+qg), PV (et=w, oa[2]).
// On j==T (or block end): flush den + oa via fire-and-forget atomicAdd into
// Den / out (pre-zeroed), reload Q for T+1, reset accumulators.
// ---------------------------------------------------------------------------
__global__ __launch_bounds__(512, 2) void attn(const uint4* __restrict__ qf,
                                               const uint4* __restrict__ kf,
                                               const uint4* __restrict__ vf,
                                               float* __restrict__ out,
                                               float* __restrict__ Den) {
    __shared__ uint4 Pb[2][2][8][64];        // 32KB, double-buffered P (64 rows)

    const int bid = blockIdx.x;
    const int slot = bid & 7;
    const int b = slot >> 1, qh = slot & 1;
    const int blk = bid >> 3;                // [0,60)
    const int c0 = (blk * NCELL) / 60;
    const int c1 = ((blk + 1) * NCELL) / 60;

    int T = 0;
    while ((T + 1) * (T + 2) / 2 <= c0) ++T;
    int j = c0 - T * (T + 1) / 2;

    const int tid = threadIdx.x, w = tid >> 6, l = tid & 63, ln = l & 31, q2 = l >> 5;
    const int ks = w & 3, qg = w >> 2;       // S^T role
    const int et = w;                        // PV role: e-tile
    const float cfac = 0.18033688011112042f; // log2(e)/sqrt(64)

    bf16x8 qv[4];
#pragma unroll
    for (int c = 0; c < 4; ++c)
        qv[c] = u4bf(qf[(((size_t)b*128 + T*4 + qh*2 + qg) * 4 + c) * 64 + l]);

    uint4 kaf[4];
#pragma unroll
    for (int c = 0; c < 4; ++c)
        kaf[c] = kf[(((size_t)b*128 + j*4 + ks) * 4 + c) * 64 + l];

    f32x16 oa[2] = {};
    float den = 0.f;
    bool dirty = false;

    for (int c = c0; c < c1; ++c) {
        const int buf = c & 1;
        const bool diag = (j == T);
        const int qsub = qh*2 + qg;

        // ---- batch V-chunk loads for THIS cell (latency covered below) ----
        uint4 vbs[8];
#pragma unroll
        for (int kc = 0; kc < 8; ++kc)
            vbs[kc] = vf[(((size_t)b*8 + et) * 256 + (size_t)j*8 + kc) * 64 + l];

        // ---- S^T (one q-sub per wave) ----
        f32x16 s = {};
#pragma unroll
        for (int cc = 0; cc < 4; ++cc)
            s = __builtin_amdgcn_mfma_f32_32x32x16_bf16(u4bf(kaf[cc]), qv[cc], s, 0, 0, 0);

        // ---- exp + mask + den + pack P -> LDS ----
        float pv[16], pd = 0.f;
#pragma unroll
        for (int r = 0; r < 16; ++r) {
            float e = __builtin_exp2f(s[r] * cfac);
            if (diag) {
                int klocal = 4*q2 + (r & 3) + 8*(r >> 2);
                if (ks*32 + klocal > qsub*32 + ln) e = 0.f;
            }
            pv[r] = e; pd += e;
        }
        den += pd;
#pragma unroll
        for (int quad = 0; quad < 4; ++quad) {
            unsigned int lo = pk2bf(pv[4*quad + 0], pv[4*quad + 1]);
            unsigned int hi = pk2bf(pv[4*quad + 2], pv[4*quad + 3]);
            int kcg = ks*2 + (quad >> 1);
            int h   = quad & 1;
            char* dst = (char*)&Pb[buf][qg][kcg][h*32 + ln] + q2*8;
            *(uint2*)dst = make_uint2(lo, hi);
        }
        __syncthreads();

        // next-cell coords; prefetch its K-frags (covered by PV)
        const bool endT = (j == T);
        const int nT = endT ? T + 1 : T;
        const int nj = endT ? 0 : j + 1;
        if (c + 1 < c1) {
#pragma unroll
            for (int cc = 0; cc < 4; ++cc)
                kaf[cc] = kf[(((size_t)b*128 + nj*4 + ks) * 4 + cc) * 64 + l];
        }

        // ---- PV: O[2 qsub][e-tile w] += P * V (V already in regs) ----
#pragma unroll
        for (int kc = 0; kc < 8; ++kc) {
            bf16x8 vb = u4bf(vbs[kc]);
#pragma unroll
            for (int qsl = 0; qsl < 2; ++qsl) {
                bf16x8 pa = u4bf(Pb[buf][qsl][kc][l]);
                oa[qsl] = __builtin_amdgcn_mfma_f32_32x32x16_bf16(pa, vb, oa[qsl], 0, 0, 0);
            }
        }
        dirty = true;

        // ---- end of row T: flush partials (fire-and-forget atomics) ----
        if (endT) {
            atomicAdd(&Den[(size_t)b*SEQ + T*128 + qh*64 + qg*32 + ln], den);
#pragma unroll
            for (int qsl = 0; qsl < 2; ++qsl)
#pragma unroll
                for (int r = 0; r < 16; ++r) {
                    int qrow = qsl*32 + (r & 3) + 8*(r >> 2) + 4*q2;
                    atomicAdd(&out[((size_t)b*SEQ + T*128 + qh*64 + qrow) * DM + et*32 + ln],
                              oa[qsl][r]);
                }
            den = 0.f;
            oa[0] = (f32x16){}; oa[1] = (f32x16){};
            dirty = false;
            if (c + 1 < c1) {   // reload Q for the next T (guarded: T+1 <= 31)
#pragma unroll
                for (int cc = 0; cc < 4; ++cc)
                    qv[cc] = u4bf(qf[(((size_t)b*128 + nT*4 + qh*2 + qg) * 4 + cc) * 64 + l]);
            }
        }
        T = nT; j = nj;
    }

    // ---- partial-T flush at block end ----
    if (dirty) {
        atomicAdd(&Den[(size_t)b*SEQ + T*128 + qh*64 + qg*32 + ln], den);
#pragma unroll
        for (int qsl = 0; qsl < 2; ++qsl)
#pragma unroll
            for (int r = 0; r < 16; ++r) {
                int qrow = qsl*32 + (r & 3) + 8*(r >> 2) + 4*q2;
                atomicAdd(&out[((size_t)b*SEQ + T*128 + qh*64 + qrow) * DM + et*32 + ln],
                          oa[qsl][r]);
            }
    }
}

// ---------------------------------------------------------------------------
// Normalize: out[b,s,:] /= Den[b,s]. grid (256, 4) x 256 thr; block = 16 rows.
// ---------------------------------------------------------------------------
__global__ __launch_bounds__(256) void norm(float* __restrict__ out,
                                            const float* __restrict__ Den) {
    const int b = blockIdx.y;
    const int r0 = blockIdx.x * 16;
    const int tid = threadIdx.x;
    float4* o4 = (float4*)(out + ((size_t)b*SEQ + r0) * DM);
#pragma unroll
    for (int i = 0; i < 4; ++i) {
        int idx = i * 256 + tid;             // 0..1023 float4 within 16 rows
        int r = idx >> 6;
        float d = Den[(size_t)b*SEQ + r0 + r];
        float4 v = o4[idx];
        v.x /= d; v.y /= d; v.z /= d; v.w /= d;
        o4[idx] = v;
    }
}

// ---------------------------------------------------------------------------
extern "C" void kernel_launch(void* const* d_in, const int* in_sizes, int n_in,
                              void* d_out, int out_size, void* d_ws, size_t ws_size,
                              hipStream_t stream) {
    const float* enc_q = (const float*)d_in[0];
    const float* enc_k = (const float*)d_in[1];
    const float* enc_v = (const float*)d_in[2];
    // d_in[3] = mask (deterministic causal triu) — not needed
    const float* Wq = (const float*)d_in[4];
    const float* Wk = (const float*)d_in[5];
    const float* Wv = (const float*)d_in[6];
    float* out = (float*)d_out;

    uint4* qf = (uint4*)d_ws;                              // 2MB
    uint4* kf = qf + 131072;                               // 2MB
    uint4* vf = kf + 131072;                               // 8MB
    float* Den = (float*)(vf + 524288);                    // [4][4096] f32, 64KB

    hipMemsetAsync(out, 0, (size_t)BATCH * SEQ * DM * sizeof(float), stream);
    hipMemsetAsync(Den, 0, (size_t)BATCH * SEQ * sizeof(float), stream);
    proj<<<dim3(64, 4, 3), 256, 0, stream>>>(enc_q, enc_k, enc_v, Wq, Wk, Wv, qf, kf, vf);
    attn<<<480, 512, 0, stream>>>(qf, kf, vf, out, Den);
    norm<<<dim3(256, 4), 256, 0, stream>>>(out, Den);
}

// Round 7
// 202.797 us; speedup vs baseline: 1.1062x; 1.0466x over previous
//
#include <hip/hip_runtime.h>

// Causal single-head attention, B=4 S=4096 Dm=256 Dqk=64, fp32 in/out.
// R15 = R12 (best verified: attn 46.0us, total 203.9, VGPR 72, 2 blocks/CU)
// + ONE change: cross-cell V prefetch by use-then-refill. R14 falsified the
// imbalance-tail theory (balanced chunks, occupancy unchanged, atomics cost
// +15us) -> reverted. R12's per-cell span ~6k cyc with no pipe >30% busy; V/K
// L2 fetch is ~2.3k cyc/CU/cell-pair and V's load->use window was only the
// S^T+exp phase (~400cyc). Now each vbs[kc] is refilled for tile jt+1 right
// after its last use in PV -> in-flight distance ~1500cyc (PV rest + next
// S^T/exp), covering even HBM-miss latency. Branchless: last iter re-loads
// its own tile (harmless, L2-hit). +4 VGPR, no new barriers, numerics
// bitwise-identical to R12.
// ws: qf 2MB + kf 2MB + vf 8MB + Op 7.34MB + Dp 98KB = 19.5MB.

#define BATCH 4
#define SEQ   4096
#define DM    256
#define DQK   64

typedef __bf16 bf16x8 __attribute__((ext_vector_type(8)));
typedef __bf16 bf16x2 __attribute__((ext_vector_type(2)));
typedef float  f32x16 __attribute__((ext_vector_type(16)));

// HW RNE float->bf16 (v_cvt_pk_bf16_f32 via compiler).
__device__ __forceinline__ unsigned short f2bf(float f) {
    __bf16 h = (__bf16)f;
    return __builtin_bit_cast(unsigned short, h);
}
__device__ __forceinline__ unsigned int pk2bf(float lo, float hi) {
    bf16x2 v = {(__bf16)lo, (__bf16)hi};    // elem0 low, elem1 high
    return __builtin_bit_cast(unsigned int, v);
}
__device__ __forceinline__ bf16x8 u4bf(uint4 u) { return __builtin_bit_cast(bf16x8, u); }

// Repack a 32x32x16 MFMA accumulator D[m][n] (C-layout: col(n)=lane&31,
// row(m)=(r&3)+8(r>>2)+4(lane>>5)) into two 1KB fragment chunks where the
// fragment k-dim = m and lane-dim = n, then store. (Verified R2/R3.)
__device__ __forceinline__ void repack_store(const f32x16& acc, int q2, int l,
                                             uint4* __restrict__ out, size_t tile_ofs_u4) {
    unsigned int d0[4], d1[4], p0[4], p1[4];
#pragma unroll
    for (int h = 0; h < 4; ++h) {
        d0[h] = pk2bf(acc[4*h + 0], acc[4*h + 1]);
        d1[h] = pk2bf(acc[4*h + 2], acc[4*h + 3]);
        p0[h] = __shfl_xor((int)d0[h], 32);
        p1[h] = __shfl_xor((int)d1[h], 32);
    }
#pragma unroll
    for (int kc = 0; kc < 2; ++kc) {
        int h = 2*kc + q2;
        uint4 v = (q2 == 0) ? make_uint4(d0[h], d1[h], p0[h], p1[h])
                            : make_uint4(p0[h], p1[h], d0[h], d1[h]);
        out[tile_ofs_u4 + (size_t)kc * 64 + l] = v;
    }
}

// R3 task map: nc=1 (T<12), 2 (12..23), 3 (24..31).
// Op slots (chunks cc>=1): T 12..23 -> 1 slot, 24..31 -> 2. 28/batch.
__device__ __forceinline__ int obase(int T) {
    return (T < 24) ? (T - 12) : 12 + (T - 24) * 2;
}
// Dp slots (all chunks of split tasks): 48/batch.
__device__ __forceinline__ int dbase(int T) {
    return (T < 24) ? (T - 12) * 2 : 24 + (T - 24) * 3;
}

// ---------------------------------------------------------------------------
// Fused projection. grid (64 s-tiles, 4 batch, 3): z=0 Q, z=1 K, z=2 V (all
// 4 e-chunks; Xv staged once).  (Unchanged from R12.)
// ---------------------------------------------------------------------------
__global__ __launch_bounds__(256) void proj(const float* __restrict__ Xq,
                                            const float* __restrict__ Xk,
                                            const float* __restrict__ Xv,
                                            const float* __restrict__ Wq,
                                            const float* __restrict__ Wk,
                                            const float* __restrict__ Wv,
                                            uint4* __restrict__ qf,
                                            uint4* __restrict__ kf,
                                            uint4* __restrict__ vf) {
    __shared__ unsigned short Xs[64][264];
    __shared__ unsigned short Ws[64][264];

    const int z = blockIdx.z;
    const int bx = blockIdx.x, b = blockIdx.y;
    const float* X = (z == 0) ? Xq : (z == 1) ? Xk : Xv;
    const float* W = (z == 0) ? Wq : (z == 1) ? Wk : Wv;
    const int s0 = bx * 64;
    const int tid = threadIdx.x, w = tid >> 6, l = tid & 63, ln = l & 31, q2 = l >> 5;

#pragma unroll
    for (int i = 0; i < 16; ++i) {
        int f = i * 256 + tid;
        int r = f >> 6, c4 = f & 63;
        float4 xv = *(const float4*)&X[((size_t)b * SEQ + s0 + r) * DM + c4 * 4];
        ushort4 h; h.x = f2bf(xv.x); h.y = f2bf(xv.y); h.z = f2bf(xv.z); h.w = f2bf(xv.w);
        *(ushort4*)&Xs[r][c4 * 4] = h;
    }

    if (z < 2) {
#pragma unroll
        for (int i = 0; i < 16; ++i) {
            int f = i * 256 + tid;
            int r = f >> 6, c4 = f & 63;
            float4 wv = *(const float4*)&W[(size_t)r * DM + c4 * 4];
            ushort4 h; h.x = f2bf(wv.x); h.y = f2bf(wv.y); h.z = f2bf(wv.z); h.w = f2bf(wv.w);
            *(ushort4*)&Ws[r][c4 * 4] = h;
        }
        __syncthreads();
        const int msub = w >> 1, nsub = w & 1;
        f32x16 a0 = {}, a1 = {};
#pragma unroll
        for (int c = 0; c < 16; c += 2) {
            bf16x8 af0 = u4bf(*(const uint4*)&Ws[msub*32 + ln][c*16 + q2*8]);
            bf16x8 bf0 = u4bf(*(const uint4*)&Xs[nsub*32 + ln][c*16 + q2*8]);
            a0 = __builtin_amdgcn_mfma_f32_32x32x16_bf16(af0, bf0, a0, 0, 0, 0);
            bf16x8 af1 = u4bf(*(const uint4*)&Ws[msub*32 + ln][(c+1)*16 + q2*8]);
            bf16x8 bf1 = u4bf(*(const uint4*)&Xs[nsub*32 + ln][(c+1)*16 + q2*8]);
            a1 = __builtin_amdgcn_mfma_f32_32x32x16_bf16(af1, bf1, a1, 0, 0, 0);
        }
        f32x16 acc = a0 + a1;
        size_t base = (((size_t)(b*128 + bx*2 + nsub)) * 4 + 2*msub) * 64;
        repack_store(acc, q2, l, (z == 0) ? qf : kf, base);
    } else {
        const int msub = w & 1, nsub = w >> 1;
        for (int ec = 0; ec < 4; ++ec) {
            __syncthreads();
#pragma unroll
            for (int i = 0; i < 16; ++i) {
                int f = i * 256 + tid;
                int r = f >> 6, c4 = f & 63;
                float4 wv = *(const float4*)&W[(size_t)(ec*64 + r) * DM + c4 * 4];
                ushort4 h; h.x = f2bf(wv.x); h.y = f2bf(wv.y); h.z = f2bf(wv.z); h.w = f2bf(wv.w);
                *(ushort4*)&Ws[r][c4 * 4] = h;
            }
            __syncthreads();
            f32x16 a0 = {}, a1 = {};
#pragma unroll
            for (int c = 0; c < 16; c += 2) {
                bf16x8 af0 = u4bf(*(const uint4*)&Xs[msub*32 + ln][c*16 + q2*8]);
                bf16x8 bf0 = u4bf(*(const uint4*)&Ws[nsub*32 + ln][c*16 + q2*8]);
                a0 = __builtin_amdgcn_mfma_f32_32x32x16_bf16(af0, bf0, a0, 0, 0, 0);
                bf16x8 af1 = u4bf(*(const uint4*)&Xs[msub*32 + ln][(c+1)*16 + q2*8]);
                bf16x8 bf1 = u4bf(*(const uint4*)&Ws[nsub*32 + ln][(c+1)*16 + q2*8]);
                a1 = __builtin_amdgcn_mfma_f32_32x32x16_bf16(af1, bf1, a1, 0, 0, 0);
            }
            f32x16 acc = a0 + a1;
            int et = ec*2 + nsub;
            size_t base = (((size_t)(b*8 + et)) * 256 + (size_t)bx*4 + msub*2) * 64;
            repack_store(acc, q2, l, vf, base);
        }
    }
}

// ---------------------------------------------------------------------------
// Attention. 480 blocks x 512 thr, 2 blocks/CU (LDS 34.5KB, ~76 VGPR).
// Block = (b, qh, task): slot = bid&7 -> b = slot>>1, qh = slot&1 (XCD pin).
// task = bid>>3. Block covers 64 q-rows x K-chunk [j0,j1).
// Wave w: S^T (ks=w&3, qg=w>>2): 4 MFMA -> 16 exp -> pack Pb[jt&1][qg][..];
// PV (et=w): oa[2 qsub] += P*V. R15: vbs[kc] refilled for jt+1 immediately
// after its PV use (cross-cell prefetch, ~1500cyc in flight); kaf prefetched
// across the barrier as before. One barrier/iter (Pb double-buffered).
// ---------------------------------------------------------------------------
__global__ __launch_bounds__(512, 2) void attn(const uint4* __restrict__ qf,
                                               const uint4* __restrict__ kf,
                                               const uint4* __restrict__ vf,
                                               float* __restrict__ out,
                                               unsigned short* __restrict__ Op,
                                               float* __restrict__ Dp) {
    __shared__ uint4 Pb[2][2][8][64];        // 32KB, double-buffered P (64 rows)
    __shared__ float denp[4][2][64];         // [ks][qg][lane]
    __shared__ float dfin[64];

    const int bid = blockIdx.x;
    const int slot = bid & 7;
    const int b = slot >> 1, qh = slot & 1;
    const int task = bid >> 3;               // [0,60)
    int T, cc, nc;
    if (task < 12)      { T = task;                cc = 0;               nc = 1; }
    else if (task < 36) { int q = task - 12; T = 12 + (q >> 1); cc = q & 1;       nc = 2; }
    else                { int q = task - 36; T = 24 + q / 3;    cc = q - 3*(q/3); nc = 3; }
    const int n = T + 1;
    const int j0 = cc * n / nc, j1 = (cc + 1) * n / nc;

    const int tid = threadIdx.x, w = tid >> 6, l = tid & 63, ln = l & 31, q2 = l >> 5;
    const int ks = w & 3, qg = w >> 2;       // S^T role
    const int qsub = qh * 2 + qg;            // global q-sub within T-tile
    const int et = w;                        // PV role: e-tile
    const float cfac = 0.18033688011112042f; // log2(e)/sqrt(64)

    bf16x8 qv[4];
#pragma unroll
    for (int c = 0; c < 4; ++c)
        qv[c] = u4bf(qf[(((size_t)b*128 + T*4 + qsub) * 4 + c) * 64 + l]);

    f32x16 oa[2] = {};
    float den = 0.f;

    uint4 kaf[4];
#pragma unroll
    for (int c = 0; c < 4; ++c)
        kaf[c] = kf[(((size_t)b*128 + j0*4 + ks) * 4 + c) * 64 + l];

    // initial V fill for tile j0 (latency covered by first S^T/exp)
    const size_t vbase = ((size_t)b*8 + et) * 256;
    uint4 vbs[8];
#pragma unroll
    for (int kc = 0; kc < 8; ++kc)
        vbs[kc] = vf[(vbase + (size_t)j0*8 + kc) * 64 + l];

    for (int jt = j0; jt < j1; ++jt) {
        const int buf = jt & 1;
        const bool diag = (jt == T);
        const int jn = (jt + 1 < j1) ? jt + 1 : jt;  // clamped next tile

        // ---- S^T (one q-sub per wave) ----
        f32x16 s = {};
#pragma unroll
        for (int c = 0; c < 4; ++c)
            s = __builtin_amdgcn_mfma_f32_32x32x16_bf16(u4bf(kaf[c]), qv[c], s, 0, 0, 0);

        // ---- exp + mask + den + pack P -> LDS ----
        float pv[16], pd = 0.f;
#pragma unroll
        for (int r = 0; r < 16; ++r) {
            float e = __builtin_exp2f(s[r] * cfac);
            if (diag) {
                int klocal = 4*q2 + (r & 3) + 8*(r >> 2);
                if (ks*32 + klocal > qsub*32 + ln) e = 0.f;
            }
            pv[r] = e; pd += e;
        }
        den += pd;
#pragma unroll
        for (int quad = 0; quad < 4; ++quad) {
            unsigned int lo = pk2bf(pv[4*quad + 0], pv[4*quad + 1]);
            unsigned int hi = pk2bf(pv[4*quad + 2], pv[4*quad + 3]);
            int kcg = ks*2 + (quad >> 1);
            int h   = quad & 1;
            char* dst = (char*)&Pb[buf][qg][kcg][h*32 + ln] + q2*8;
            *(uint2*)dst = make_uint2(lo, hi);
        }
        __syncthreads();
        // ---- prefetch next K-frags (covered by PV) ----
        if (jt + 1 < j1) {
#pragma unroll
            for (int c = 0; c < 4; ++c)
                kaf[c] = kf[(((size_t)b*128 + (jt+1)*4 + ks) * 4 + c) * 64 + l];
        }
        // ---- PV with use-then-refill: vbs[kc] -> tile jn after last use ----
#pragma unroll
        for (int kc = 0; kc < 8; ++kc) {
            bf16x8 vb = u4bf(vbs[kc]);
            vbs[kc] = vf[(vbase + (size_t)jn*8 + kc) * 64 + l];
#pragma unroll
            for (int qsl = 0; qsl < 2; ++qsl) {
                bf16x8 pa = u4bf(Pb[buf][qsl][kc][l]);
                oa[qsl] = __builtin_amdgcn_mfma_f32_32x32x16_bf16(pa, vb, oa[qsl], 0, 0, 0);
            }
        }
    }

    // ---- den reduction across ks-waves/halves (order matches R8 bitwise) ----
    denp[ks][qg][l] = den;
    __syncthreads();
    if (tid < 64) {
        int qgl = tid >> 5, qln = tid & 31;
        float sden = 0.f;
#pragma unroll
        for (int p = 0; p < 4; ++p)
#pragma unroll
            for (int hh = 0; hh < 2; ++hh)
                sden += denp[p][qgl][hh*32 + qln];
        dfin[tid] = (nc == 1) ? 1.0f / sden : sden;
    }
    __syncthreads();

    if (nc == 1) {
#pragma unroll
        for (int qsl = 0; qsl < 2; ++qsl)
#pragma unroll
            for (int r = 0; r < 16; ++r) {
                int qrow = qsl*32 + (r & 3) + 8*(r >> 2) + 4*q2;
                out[((size_t)b*SEQ + T*128 + qh*64 + qrow) * DM + et*32 + ln] = oa[qsl][r] * dfin[qrow];
            }
    } else if (cc == 0) {
        // chunk 0: unnormalized fp32 straight into out (combine divides later)
#pragma unroll
        for (int qsl = 0; qsl < 2; ++qsl)
#pragma unroll
            for (int r = 0; r < 16; ++r) {
                int qrow = qsl*32 + (r & 3) + 8*(r >> 2) + 4*q2;
                out[((size_t)b*SEQ + T*128 + qh*64 + qrow) * DM + et*32 + ln] = oa[qsl][r];
            }
        if (tid < 64) Dp[((size_t)b*48 + dbase(T)) * 128 + qh*64 + tid] = dfin[tid];
    } else {
        size_t pidx = (size_t)b*28 + obase(T) + (cc - 1);
#pragma unroll
        for (int qsl = 0; qsl < 2; ++qsl)
#pragma unroll
            for (int r = 0; r < 16; ++r) {
                int qrow = qsl*32 + (r & 3) + 8*(r >> 2) + 4*q2;
                Op[(pidx*128 + qh*64 + qrow) * DM + et*32 + ln] = f2bf(oa[qsl][r]);
            }
        if (tid < 64) Dp[((size_t)b*48 + dbase(T) + cc) * 128 + qh*64 + tid] = dfin[tid];
    }
}

// ---------------------------------------------------------------------------
// Combine partials for T in [12,32). grid (20, 4, 4 q-quarters) x 256 thr.
// out holds chunk-0's unnormalized fp32; add bf16 chunks >=1, divide by den.
// (Unchanged.)
// ---------------------------------------------------------------------------
__global__ __launch_bounds__(256) void combine(const unsigned short* __restrict__ Op,
                                               const float* __restrict__ Dp,
                                               float* __restrict__ out) {
    const int T = 12 + blockIdx.x, b = blockIdx.y, qq = blockIdx.z;
    const int nc = (T < 24) ? 2 : 3;
    const int t = threadIdx.x;
    const size_t db = (size_t)b*48 + dbase(T);
    const size_t pb = (size_t)b*28 + obase(T);
#pragma unroll 4
    for (int r = 0; r < 32; ++r) {
        int q = qq*32 + r;
        size_t oofs = ((size_t)b*SEQ + T*128 + q) * DM + t;
        float sum = out[oofs];
        float dsum = 0.f;
        for (int c = 0; c < nc; ++c) dsum += Dp[(db + c)*128 + q];
        for (int c = 1; c < nc; ++c) {
            unsigned int uv = Op[((pb + c - 1)*128 + q) * DM + t];
            sum += __builtin_bit_cast(float, uv << 16);
        }
        out[oofs] = sum / dsum;
    }
}

// ---------------------------------------------------------------------------
extern "C" void kernel_launch(void* const* d_in, const int* in_sizes, int n_in,
                              void* d_out, int out_size, void* d_ws, size_t ws_size,
                              hipStream_t stream) {
    const float* enc_q = (const float*)d_in[0];
    const float* enc_k = (const float*)d_in[1];
    const float* enc_v = (const float*)d_in[2];
    // d_in[3] = mask (deterministic causal triu) — not needed
    const float* Wq = (const float*)d_in[4];
    const float* Wk = (const float*)d_in[5];
    const float* Wv = (const float*)d_in[6];
    float* out = (float*)d_out;

    uint4* qf = (uint4*)d_ws;                              // 2MB
    uint4* kf = qf + 131072;                               // 2MB
    uint4* vf = kf + 131072;                               // 8MB
    unsigned short* Op = (unsigned short*)(vf + 524288);   // [4][28][128][256] bf16, 7.34MB
    float* Dp = (float*)(Op + (size_t)4*28*128*256);       // [4][48][128] f32, 98KB

    proj<<<dim3(64, 4, 3), 256, 0, stream>>>(enc_q, enc_k, enc_v, Wq, Wk, Wv, qf, kf, vf);
    attn<<<480, 512, 0, stream>>>(qf, kf, vf, out, Op, Dp);
    combine<<<dim3(20, 4, 4), 256, 0, stream>>>(Op, Dp, out);
}